// Round 9
// baseline (507.747 us; speedup 1.0000x reference)
//
#include <hip/hip_runtime.h>

// CRF NLL forward loss. B=256, T=2048, K2=52 (50 labels + START=50 + STOP=51).
// Linear-domain bidirectional recurrence, one chain per wave (R9 structure):
//   wave 0 (fwd): v <- E_t * (M v),   t = 0..h-1      (h = L/2)
//   wave 1 (bwd): u <- M^T (E_t * u), t = L-1..h
//   score = ln2*(Cf + Cb + log2(dot(u,v)))
//
// R15: broadcast-engine scorecard (cyc/chain-step): LDS wr+13xb128 = 638 (R9),
// ds_bpermute x52 = 795 (R14, DS-pipe serializes), paired chains = 483 eff. but
// doubles critical-wave steps (R13, net loss). Remaining engine that moves data
// cross-lane at VALU speed with no wait-counters: DPP. Rewrite the matvec in
// ROTATED coordinates: pad v to 64 comps (lanes 52-63 = 0, killed by DG = 0),
// per-lane diagonal table DG_r = M[n][(n +/- r) & 63], step r does
// y += DG_r * rot^r(v) with rot = v_mov_dpp wave_ror:1 (pure VALU, 2cyc, no
// lgkmcnt). Two parallel rotation chains (2nd seeded by shfl_xor(vv,32)
// computed at the PREVIOUS step's end -> latency hidden) give 4-instr dep
// spacing -> issue-bound ~300-360 cyc/step vs 638. wave_ror direction
// ambiguity (lane gets n+1 vs n-1) resolved by a runtime probe -> ddir in
// {1,63} used only in DG construction: correct under either convention.
// Renorm magnitude: 1 readlane of the stable prev state (off critical path).
// waves_per_eu(1,1) + volatile-asm DG defs keep the table resident (R11-R13).

#define B_    256
#define T_    2048
#define K2_   52
#define LOG2E_ 1.4426950408889634f
#define LN2_   0.6931471805599453f

__device__ __forceinline__ int imin(int a, int b) { return a < b ? a : b; }
__device__ __forceinline__ int imax(int a, int b) { return a > b ? a : b; }
__device__ __forceinline__ float rdlane(float v, int src) {
  return __uint_as_float(__builtin_amdgcn_readlane(__float_as_uint(v), src));
}
// wave_ror:1 (dpp_ctrl 0x13C): full-wave rotate by one lane. VALU-speed.
__device__ __forceinline__ float rotf(float x) {
  return __int_as_float(__builtin_amdgcn_update_dpp(
      __float_as_int(x), __float_as_int(x), 0x13C, 0xF, 0xF, false));
}

#define X2F(e) __builtin_amdgcn_exp2f((e) * LOG2E_)

#define FORALL64(F) \
  F(0) F(1) F(2) F(3) F(4) F(5) F(6) F(7) F(8) F(9) F(10) F(11) F(12) F(13) \
  F(14) F(15) F(16) F(17) F(18) F(19) F(20) F(21) F(22) F(23) F(24) F(25) \
  F(26) F(27) F(28) F(29) F(30) F(31) F(32) F(33) F(34) F(35) F(36) F(37) \
  F(38) F(39) F(40) F(41) F(42) F(43) F(44) F(45) F(46) F(47) F(48) F(49) \
  F(50) F(51) F(52) F(53) F(54) F(55) F(56) F(57) F(58) F(59) F(60) F(61) \
  F(62) F(63)

// Diagonal M tables (volatile asm def: unsinkable -> stays register-resident).
// At rotation r, this lane's rolling value holds v[(lane + ddir*r) & 63], so
// DG_r must be M[row=lane][col=(lane + ddir*r) & 63] (fwd) / M[col][row] (bwd).
// Out-of-range row/col -> exp2(-1e30) = 0 exactly (kills padding lanes).
#define DECLDG_F(r) float DG_##r; { \
  int _col = (lane + ddir * (r)) & 63; \
  int _cc  = imin(_col, K2_ - 1); \
  float _t = (lane < K2_ && _col < K2_) ? tr[n * K2_ + _cc] * LOG2E_ : -1.0e30f; \
  asm volatile("v_exp_f32 %0, %1\n\ts_nop 1" : "=v"(DG_##r) : "v"(_t)); }
#define DECLDG_B(r) float DG_##r; { \
  int _col = (lane + ddir * (r)) & 63; \
  int _cc  = imin(_col, K2_ - 1); \
  float _t = (lane < K2_ && _col < K2_) ? tr[_cc * K2_ + n] * LOG2E_ : -1.0e30f; \
  asm volatile("v_exp_f32 %0, %1\n\ts_nop 1" : "=v"(DG_##r) : "v"(_t)); }

// Interleaved pair list: chain A covers r = 0..31, chain B covers r = 32..63.
// Accumulators: A -> _a0.._a3, B -> _a4.._a7 (dep depth 8 per acc).
#define MVP(k, k32, cA, cB) \
  _a##cA = fmaf(DG_##k,   _rA, _a##cA);  _rA = rotf(_rA); \
  _a##cB = fmaf(DG_##k32, _rB, _a##cB);  _rB = rotf(_rB);

#define FOR32P(F) \
  F(0,32,0,4)  F(1,33,1,5)  F(2,34,2,6)  F(3,35,3,7) \
  F(4,36,0,4)  F(5,37,1,5)  F(6,38,2,6)  F(7,39,3,7) \
  F(8,40,0,4)  F(9,41,1,5)  F(10,42,2,6) F(11,43,3,7) \
  F(12,44,0,4) F(13,45,1,5) F(14,46,2,6) F(15,47,3,7) \
  F(16,48,0,4) F(17,49,1,5) F(18,50,2,6) F(19,51,3,7) \
  F(20,52,0,4) F(21,53,1,5) F(22,54,2,6) F(23,55,3,7) \
  F(24,56,0,4) F(25,57,1,5) F(26,58,2,6) F(27,59,3,7) \
  F(28,60,0,4) F(29,61,1,5) F(30,62,2,6) F(31,63,3,7)

// y_n = sum_r DG_r * v[(n + ddir*r) & 63].  SRC32 = shfl_xor(SRC, 32), computed
// at the previous step's end so its DS latency is already hidden.
#define MATVEC64(SRC, SRC32, OUTY) \
    float _rA = (SRC); \
    float _rB = (SRC32); \
    float _a0=0.f,_a1=0.f,_a2=0.f,_a3=0.f,_a4=0.f,_a5=0.f,_a6=0.f,_a7=0.f; \
    FOR32P(MVP) \
    float OUTY = ((_a0+_a1)+(_a2+_a3)) + ((_a4+_a5)+(_a6+_a7));

// ---- forward steps: v' = E_t * (M v); renorm comp 50 (START row, >0) -------
#define FSTEP_R(EV, NEWIDX) do {                                \
    float _ne = emb[(size_t)(NEWIDX) * K2_ + n];                \
    float _m  = rdlane(vv, 50);                                 \
    float _inv = __builtin_amdgcn_rcpf(_m);                     \
    C += __builtin_amdgcn_logf(_m);                             \
    MATVEC64(vv, vx, _y)                                        \
    vv = _y * (_inv * X2F(EV));                                 \
    vx = __shfl_xor(vv, 32, 64);                                \
    EV = _ne;                                                   \
  } while (0)
#define FSTEP_N(EV, NEWIDX) do {                                \
    float _ne = emb[(size_t)(NEWIDX) * K2_ + n];                \
    MATVEC64(vv, vx, _y)                                        \
    vv = _y * X2F(EV);                                          \
    vx = __shfl_xor(vv, 32, 64);                                \
    EV = _ne;                                                   \
  } while (0)

// ---- backward steps: state vv holds w = E.*u; u' = M^T w; w' = u'*E_next ---
#define BSTEP_R(EV, NEWIDX) do {                                \
    float _ne = emb[(size_t)(NEWIDX) * K2_ + n];                \
    float _m  = rdlane(vv, 0);                                  \
    float _inv = __builtin_amdgcn_rcpf(_m);                     \
    C += __builtin_amdgcn_logf(_m);                             \
    MATVEC64(vv, vx, _y)                                        \
    ub = _y * _inv;                                             \
    vv = ub * X2F(EV);                                          \
    vx = __shfl_xor(vv, 32, 64);                                \
    EV = _ne;                                                   \
  } while (0)
#define BSTEP_N(EV, NEWIDX) do {                                \
    float _ne = emb[(size_t)(NEWIDX) * K2_ + n];                \
    MATVEC64(vv, vx, _y)                                        \
    ub = _y;                                                    \
    vv = ub * X2F(EV);                                          \
    vx = __shfl_xor(vv, 32, 64);                                \
    EV = _ne;                                                   \
  } while (0)

__global__ __launch_bounds__(128)
__attribute__((amdgpu_waves_per_eu(1, 1)))
void crf_fwd_kernel(const float* __restrict__ em,
                    const float* __restrict__ tr,
                    const int*  __restrict__ len,
                    const int*  __restrict__ lab,
                    float* __restrict__ per_b)
{
  const int b    = blockIdx.x;
  const int tid  = threadIdx.x;                      // 128 = 2 waves
  const int wave = tid >> 6;
  const int lane = tid & 63;
  const int n    = (lane < K2_) ? lane : (K2_ - 1);  // clamped row for loads
  const int L    = len[b];
  const int h    = L >> 1;                           // fwd steps; bwd L-h
  const float* emb = em + (size_t)b * (T_ * K2_);

  __shared__ float sU[64];     // backward wave's final u (handoff only)
  __shared__ float sCb[1];     // backward wave's log-offset
  __shared__ float sG[2];      // per-wave gold partials

  // Probe wave_ror:1 direction: rotate the lane index once; if lane 0 now
  // holds 1, the convention is "lane n gets lane (n+1)" -> ddir = +1; else
  // lane 0 holds 63 -> "lane n gets lane (n-1)" -> ddir = -1 (== 63 mod 64).
  int _pv = __builtin_amdgcn_update_dpp(lane, lane, 0x13C, 0xF, 0xF, false);
  const int ddir = (__builtin_amdgcn_readlane(_pv, 0) == 1) ? 1 : 63;

  float vv, vx, C = 0.0f;

  if (wave == 0) {
    // ---------------- forward half: h steps, rows 0..h-1 ----------------
    FORALL64(DECLDG_F)
    vv = (lane == 50) ? 1.0f : 0.0f;       // lanes >= 52 exactly 0
    vx = __shfl_xor(vv, 32, 64);
    float e0 = emb[0 * K2_ + n];
    float e1 = emb[1 * K2_ + n];
    float e2 = emb[2 * K2_ + n];
    float e3 = emb[3 * K2_ + n];
    int t = 0;
    for (; t + 4 <= h; t += 4) {
      int i4 = imin(t + 4, T_ - 1), i5 = imin(t + 5, T_ - 1);
      int i6 = imin(t + 6, T_ - 1), i7 = imin(t + 7, T_ - 1);
      FSTEP_R(e0, i4);
      FSTEP_N(e1, i5);
      FSTEP_N(e2, i6);
      FSTEP_N(e3, i7);
    }
    int rem = h - t;
    if (rem > 0) FSTEP_R(e0, T_ - 1);
    if (rem > 1) FSTEP_N(e1, T_ - 1);
    if (rem > 2) FSTEP_N(e2, T_ - 1);
  } else {
    // ---------------- backward half: L-h steps, rows L-1 down to h ------
    FORALL64(DECLDG_B)
    float ub = (lane < K2_) ? X2F(tr[(K2_ - 1) * K2_ + n]) : 0.0f;  // u_0 = s
    int cnt = L - h;
    float e0 = emb[(size_t)(L - 1) * K2_ + n];            // E for first step
    float eA = emb[(size_t)imax(L - 2, 0) * K2_ + n];
    float eB = emb[(size_t)imax(L - 3, 0) * K2_ + n];
    float eC = emb[(size_t)imax(L - 4, 0) * K2_ + n];
    float eD = emb[(size_t)imax(L - 5, 0) * K2_ + n];
    vv = ub * X2F(e0);                                    // w_0 = E_{L-1}.*u_0
    vx = __shfl_xor(vv, 32, 64);
    int s = 0;
    for (; s + 4 <= cnt; s += 4) {
      int j4 = imax(L - 6 - s, 0), j5 = imax(L - 7 - s, 0);
      int j6 = imax(L - 8 - s, 0), j7 = imax(L - 9 - s, 0);
      BSTEP_R(eA, j4);
      BSTEP_N(eB, j5);
      BSTEP_N(eC, j6);
      BSTEP_N(eD, j7);
    }
    int rem = cnt - s;
    if (rem > 0) BSTEP_R(eA, 0);
    if (rem > 1) BSTEP_N(eB, 0);
    if (rem > 2) BSTEP_N(eC, 0);

    sU[lane] = ub;              // publish final u
    if (lane == 0) sCb[0] = C;
  }

  // ---- gold score (both waves, stride 128) ----
  float gold = 0.0f;
  const int* labb = lab + b * T_;
  for (int tt = tid; tt < L; tt += 128) {
    int l1 = labb[tt];
    int l0 = (tt == 0) ? 50 : labb[tt - 1];
    gold += emb[(size_t)tt * K2_ + l1] + tr[l1 * K2_ + l0];
  }
  if (tid == 0) gold += tr[(K2_ - 1) * K2_ + labb[L - 1]];  // STOP <- last label
#pragma unroll
  for (int off = 32; off >= 1; off >>= 1)
    gold += __shfl_xor(gold, off, 64);
  if (lane == 0) sG[wave] = gold;

  __syncthreads();

  if (wave == 0) {
    // dot(u, v) + combine log-offsets
    float x = (lane < K2_) ? vv * sU[lane] : 0.0f;
#pragma unroll
    for (int off = 32; off >= 1; off >>= 1)
      x += __shfl_xor(x, off, 64);
    float fwd = (C + sCb[0] + __builtin_amdgcn_logf(x)) * LN2_;
    if (lane == 0) per_b[b] = fwd - (sG[0] + sG[1]);
  }
}

__global__ void reduce_mean_kernel(const float* __restrict__ per_b,
                                   float* __restrict__ out)
{
  const int tid = threadIdx.x;  // 256
  float v = per_b[tid];
#pragma unroll
  for (int off = 32; off >= 1; off >>= 1) v += __shfl_xor(v, off, 64);
  __shared__ float s[4];
  if ((tid & 63) == 0) s[tid >> 6] = v;
  __syncthreads();
  if (tid == 0) out[0] = ((s[0] + s[1]) + (s[2] + s[3])) * (1.0f / (float)B_);
}

extern "C" void kernel_launch(void* const* d_in, const int* in_sizes, int n_in,
                              void* d_out, int out_size, void* d_ws, size_t ws_size,
                              hipStream_t stream) {
  const float* em  = (const float*)d_in[0];   // [B,T,K2] f32
  const float* tr  = (const float*)d_in[1];   // [K2,K2]  f32
  const int*   len = (const int*)d_in[2];     // [B] i32
  const int*   lab = (const int*)d_in[3];     // [B,T] i32
  float* out = (float*)d_out;
  float* ws  = (float*)d_ws;                  // 256 floats of per-batch scores

  crf_fwd_kernel<<<B_, 128, 0, stream>>>(em, tr, len, lab, ws);
  reduce_mean_kernel<<<1, 256, 0, stream>>>(ws, out);
}

// Round 10
// 390.758 us; speedup vs baseline: 1.2994x; 1.2994x over previous
//
#include <hip/hip_runtime.h>

// CRF NLL forward loss. B=256, T=2048, K2=52 (50 labels + START=50 + STOP=51).
// Linear-domain bidirectional recurrence, one chain per wave (R9 structure):
//   wave 0 (fwd): v <- E_t * (M v),   t = 0..h-1      (h = L/2)
//   wave 1 (bwd): u <- M^T (E_t * u), t = L-1..h
//   score = ln2*(Cf + Cb + log2(dot(u,v)))
//
// R16: broadcast-engine scorecard (cyc/chain-step, measured): LDS wr+13xb128 =
// 638 (R9) < readlane = 700 (R0) < bpermute = 795 (R14) < DPP = 940 (R15);
// chain-packing never wins (wall = len x step, R13). So: keep the LDS engine
// and cut its ~250cyc of compiler-waitcnt slack by hand-scheduling. ONE asm
// block issues ds_write_b32(vv) + 13x ds_read_b128 (renorm quad FIRST). DS ops
// complete IN ORDER per wave -> after s_waitcnt lgkmcnt(12-k), quad k has
// landed. Each wait + sched_barrier(0) (rule #18) gates one 4-FMA group; the
// renorm rcp/log starts at the first wait, parallel to the read drain.
// Emission loads are VMEM (global_load/vmcnt) -> don't touch lgkm counts.
// Expected step ~370-450 vs 638. waves_per_eu(1,1) + volatile-asm M defs.

#define B_    256
#define T_    2048
#define K2_   52
#define LOG2E_ 1.4426950408889634f
#define LN2_   0.6931471805599453f

typedef float vf4 __attribute__((ext_vector_type(4)));

__device__ __forceinline__ int imin(int a, int b) { return a < b ? a : b; }
__device__ __forceinline__ int imax(int a, int b) { return a > b ? a : b; }

#define X2F(e) __builtin_amdgcn_exp2f((e) * LOG2E_)

#define FORALL52(F) \
  F(0) F(1) F(2) F(3) F(4) F(5) F(6) F(7) F(8) F(9) F(10) F(11) F(12) F(13) \
  F(14) F(15) F(16) F(17) F(18) F(19) F(20) F(21) F(22) F(23) F(24) F(25) \
  F(26) F(27) F(28) F(29) F(30) F(31) F(32) F(33) F(34) F(35) F(36) F(37) \
  F(38) F(39) F(40) F(41) F(42) F(43) F(44) F(45) F(46) F(47) F(48) F(49) \
  F(50) F(51)

// M defs: volatile asm (unsinkable) so the 52 values stay register-resident.
// Forward: lane n holds row n (MF_i = exp(tr[n][i])). Backward: col n.
#define DECLMF(i) float MF_##i; { float _t = tr[n * K2_ + i] * LOG2E_; \
  asm volatile("v_exp_f32 %0, %1\n\ts_nop 1" : "=v"(MF_##i) : "v"(_t)); }
#define DECLMB(i) float MB_##i; { float _t = tr[i * K2_ + n] * LOG2E_; \
  asm volatile("v_exp_f32 %0, %1\n\ts_nop 1" : "=v"(MB_##i) : "v"(_t)); }

// Counted wait + scheduling fence (rule #18: FMAs must not hoist above the
// wait that guarantees their operand quad has landed).
#define WAITL(N) do { asm volatile("s_waitcnt lgkmcnt(" #N ")"); \
                      __builtin_amdgcn_sched_barrier(0); } while (0)

#define AQ4(MP, Q, i0,i1,i2,i3, A0,A1,A2,A3) \
  A0 = fmaf(MP##_##i0, (Q).x, A0); \
  A1 = fmaf(MP##_##i1, (Q).y, A1); \
  A2 = fmaf(MP##_##i2, (Q).z, A2); \
  A3 = fmaf(MP##_##i3, (Q).w, A3);

// One DS transaction set: write current state, read all 13 broadcast quads.
// FWD order: renorm quad (comps 48..51, offset 192) first, then 0..176.
#define DSBLK_F(VVIN) \
  vf4 _qc,_q0,_q1,_q2,_q3,_q4,_q5,_q6,_q7,_q8,_q9,_q10,_q11; \
  asm volatile( \
    "s_nop 1\n\t" \
    "ds_write_b32 %13, %15\n\t" \
    "ds_read_b128 %0, %14 offset:192\n\t" \
    "ds_read_b128 %1, %14 offset:0\n\t" \
    "ds_read_b128 %2, %14 offset:16\n\t" \
    "ds_read_b128 %3, %14 offset:32\n\t" \
    "ds_read_b128 %4, %14 offset:48\n\t" \
    "ds_read_b128 %5, %14 offset:64\n\t" \
    "ds_read_b128 %6, %14 offset:80\n\t" \
    "ds_read_b128 %7, %14 offset:96\n\t" \
    "ds_read_b128 %8, %14 offset:112\n\t" \
    "ds_read_b128 %9, %14 offset:128\n\t" \
    "ds_read_b128 %10, %14 offset:144\n\t" \
    "ds_read_b128 %11, %14 offset:160\n\t" \
    "ds_read_b128 %12, %14 offset:176\n\t" \
    : "=&v"(_qc),"=&v"(_q0),"=&v"(_q1),"=&v"(_q2),"=&v"(_q3),"=&v"(_q4), \
      "=&v"(_q5),"=&v"(_q6),"=&v"(_q7),"=&v"(_q8),"=&v"(_q9),"=&v"(_q10), \
      "=&v"(_q11) \
    : "v"(waddr), "v"(raddr), "v"(VVIN));

// BWD order: renorm quad (comps 0..3, offset 0) first, then 16..192.
#define DSBLK_B(VVIN) \
  vf4 _q0,_q1,_q2,_q3,_q4,_q5,_q6,_q7,_q8,_q9,_q10,_q11,_qc; \
  asm volatile( \
    "s_nop 1\n\t" \
    "ds_write_b32 %13, %15\n\t" \
    "ds_read_b128 %0, %14 offset:0\n\t" \
    "ds_read_b128 %1, %14 offset:16\n\t" \
    "ds_read_b128 %2, %14 offset:32\n\t" \
    "ds_read_b128 %3, %14 offset:48\n\t" \
    "ds_read_b128 %4, %14 offset:64\n\t" \
    "ds_read_b128 %5, %14 offset:80\n\t" \
    "ds_read_b128 %6, %14 offset:96\n\t" \
    "ds_read_b128 %7, %14 offset:112\n\t" \
    "ds_read_b128 %8, %14 offset:128\n\t" \
    "ds_read_b128 %9, %14 offset:144\n\t" \
    "ds_read_b128 %10, %14 offset:160\n\t" \
    "ds_read_b128 %11, %14 offset:176\n\t" \
    "ds_read_b128 %12, %14 offset:192\n\t" \
    : "=&v"(_q0),"=&v"(_q1),"=&v"(_q2),"=&v"(_q3),"=&v"(_q4),"=&v"(_q5), \
      "=&v"(_q6),"=&v"(_q7),"=&v"(_q8),"=&v"(_q9),"=&v"(_q10),"=&v"(_q11), \
      "=&v"(_qc) \
    : "v"(waddr), "v"(raddr), "v"(VVIN));

// FWD matvec: quad k gated by lgkmcnt(12-k); accs alternate a0-3 / a4-7.
#define MVBODY_F \
    float _a0=0.f,_a1=0.f,_a2=0.f,_a3=0.f,_a4=0.f,_a5=0.f,_a6=0.f,_a7=0.f; \
    WAITL(11); AQ4(MF,_q0,  0, 1, 2, 3, _a4,_a5,_a6,_a7) \
    WAITL(10); AQ4(MF,_q1,  4, 5, 6, 7, _a0,_a1,_a2,_a3) \
    WAITL(9);  AQ4(MF,_q2,  8, 9,10,11, _a4,_a5,_a6,_a7) \
    WAITL(8);  AQ4(MF,_q3, 12,13,14,15, _a0,_a1,_a2,_a3) \
    WAITL(7);  AQ4(MF,_q4, 16,17,18,19, _a4,_a5,_a6,_a7) \
    WAITL(6);  AQ4(MF,_q5, 20,21,22,23, _a0,_a1,_a2,_a3) \
    WAITL(5);  AQ4(MF,_q6, 24,25,26,27, _a4,_a5,_a6,_a7) \
    WAITL(4);  AQ4(MF,_q7, 28,29,30,31, _a0,_a1,_a2,_a3) \
    WAITL(3);  AQ4(MF,_q8, 32,33,34,35, _a4,_a5,_a6,_a7) \
    WAITL(2);  AQ4(MF,_q9, 36,37,38,39, _a0,_a1,_a2,_a3) \
    WAITL(1);  AQ4(MF,_q10,40,41,42,43, _a4,_a5,_a6,_a7) \
    WAITL(0);  AQ4(MF,_q11,44,45,46,47, _a0,_a1,_a2,_a3) \
    AQ4(MF,_qc,48,49,50,51, _a4,_a5,_a6,_a7) \
    float _y = ((_a0+_a1)+(_a2+_a3)) + ((_a4+_a5)+(_a6+_a7));

#define MVBODY_B \
    float _a0=0.f,_a1=0.f,_a2=0.f,_a3=0.f,_a4=0.f,_a5=0.f,_a6=0.f,_a7=0.f; \
    AQ4(MB,_q0,  0, 1, 2, 3, _a0,_a1,_a2,_a3) \
    WAITL(11); AQ4(MB,_q1,  4, 5, 6, 7, _a4,_a5,_a6,_a7) \
    WAITL(10); AQ4(MB,_q2,  8, 9,10,11, _a0,_a1,_a2,_a3) \
    WAITL(9);  AQ4(MB,_q3, 12,13,14,15, _a4,_a5,_a6,_a7) \
    WAITL(8);  AQ4(MB,_q4, 16,17,18,19, _a0,_a1,_a2,_a3) \
    WAITL(7);  AQ4(MB,_q5, 20,21,22,23, _a4,_a5,_a6,_a7) \
    WAITL(6);  AQ4(MB,_q6, 24,25,26,27, _a0,_a1,_a2,_a3) \
    WAITL(5);  AQ4(MB,_q7, 28,29,30,31, _a4,_a5,_a6,_a7) \
    WAITL(4);  AQ4(MB,_q8, 32,33,34,35, _a0,_a1,_a2,_a3) \
    WAITL(3);  AQ4(MB,_q9, 36,37,38,39, _a4,_a5,_a6,_a7) \
    WAITL(2);  AQ4(MB,_q10,40,41,42,43, _a0,_a1,_a2,_a3) \
    WAITL(1);  AQ4(MB,_q11,44,45,46,47, _a4,_a5,_a6,_a7) \
    WAITL(0);  AQ4(MB,_qc, 48,49,50,51, _a0,_a1,_a2,_a3) \
    float _y = ((_a0+_a1)+(_a2+_a3)) + ((_a4+_a5)+(_a6+_a7));

// ---- forward steps: v' = E_t * (M v); renorm comp 50 = _qc.z (after W12) ----
#define FSTEP_R(EV, NEWIDX) do {                                \
    float _ne = emb[(size_t)(NEWIDX) * K2_ + n];                \
    float _E  = X2F(EV);                                        \
    DSBLK_F(vv)                                                 \
    WAITL(12);                                                  \
    float _m   = _qc.z;                                         \
    float _inv = __builtin_amdgcn_rcpf(_m);                     \
    C += __builtin_amdgcn_logf(_m);                             \
    MVBODY_F                                                    \
    vv = _y * (_inv * _E);                                      \
    EV = _ne;                                                   \
  } while (0)
#define FSTEP_N(EV, NEWIDX) do {                                \
    float _ne = emb[(size_t)(NEWIDX) * K2_ + n];                \
    float _E  = X2F(EV);                                        \
    DSBLK_F(vv)                                                 \
    WAITL(12);                                                  \
    MVBODY_F                                                    \
    vv = _y * _E;                                               \
    EV = _ne;                                                   \
  } while (0)

// ---- backward steps: vv holds w = E.*u; u' = M^T w; w' = u' * E_next -------
#define BSTEP_R(EV, NEWIDX) do {                                \
    float _ne = emb[(size_t)(NEWIDX) * K2_ + n];                \
    float _E  = X2F(EV);                                        \
    DSBLK_B(vv)                                                 \
    WAITL(12);                                                  \
    float _m   = _q0.x;                                         \
    float _inv = __builtin_amdgcn_rcpf(_m);                     \
    C += __builtin_amdgcn_logf(_m);                             \
    MVBODY_B                                                    \
    ub = _y * _inv;                                             \
    vv = ub * _E;                                               \
    EV = _ne;                                                   \
  } while (0)
#define BSTEP_N(EV, NEWIDX) do {                                \
    float _ne = emb[(size_t)(NEWIDX) * K2_ + n];                \
    float _E  = X2F(EV);                                        \
    DSBLK_B(vv)                                                 \
    WAITL(12);                                                  \
    MVBODY_B                                                    \
    ub = _y;                                                    \
    vv = ub * _E;                                               \
    EV = _ne;                                                   \
  } while (0)

__global__ __launch_bounds__(128)
__attribute__((amdgpu_waves_per_eu(1, 1)))
void crf_fwd_kernel(const float* __restrict__ em,
                    const float* __restrict__ tr,
                    const int*  __restrict__ len,
                    const int*  __restrict__ lab,
                    float* __restrict__ per_b)
{
  const int b    = blockIdx.x;
  const int tid  = threadIdx.x;                      // 128 = 2 waves
  const int wave = tid >> 6;
  const int lane = tid & 63;
  const int n    = (lane < K2_) ? lane : (K2_ - 1);  // lanes 52..63 mirror 51
  const int L    = len[b];
  const int h    = L >> 1;                           // fwd steps; bwd L-h
  const float* emb = em + (size_t)b * (T_ * K2_);

  __shared__ __align__(16) float sV[2][64];   // per-wave broadcast buffer
  __shared__ float sU[64];     // backward wave's final u (handoff only)
  __shared__ float sCb[1];     // backward wave's log-offset
  __shared__ float sG[2];      // per-wave gold partials

  // LDS byte addresses for the asm ds ops (addrspace(3) offset = low 32 bits
  // of the flat-cast pointer on gfx9+; shared aperture low half is 0).
  const unsigned base  = (unsigned)(size_t)(&sV[wave][0]);
  const unsigned waddr = base + (unsigned)lane * 4u;
  const unsigned raddr = base;

  float vv, C = 0.0f;

  if (wave == 0) {
    // ---------------- forward half: h steps, rows 0..h-1 ----------------
    FORALL52(DECLMF)
    vv = (lane == 50) ? 1.0f : 0.0f;
    float e0 = emb[0 * K2_ + n];
    float e1 = emb[1 * K2_ + n];
    float e2 = emb[2 * K2_ + n];
    float e3 = emb[3 * K2_ + n];
    int t = 0;
    for (; t + 4 <= h; t += 4) {
      int i4 = imin(t + 4, T_ - 1), i5 = imin(t + 5, T_ - 1);
      int i6 = imin(t + 6, T_ - 1), i7 = imin(t + 7, T_ - 1);
      FSTEP_R(e0, i4);
      FSTEP_N(e1, i5);
      FSTEP_N(e2, i6);
      FSTEP_N(e3, i7);
    }
    int rem = h - t;
    if (rem > 0) FSTEP_R(e0, T_ - 1);
    if (rem > 1) FSTEP_N(e1, T_ - 1);
    if (rem > 2) FSTEP_N(e2, T_ - 1);
  } else {
    // ---------------- backward half: L-h steps, rows L-1 down to h ------
    FORALL52(DECLMB)
    float ub = X2F(tr[(K2_ - 1) * K2_ + n]);              // u_0 = s (STOP row)
    int cnt = L - h;
    float e0 = emb[(size_t)(L - 1) * K2_ + n];            // E for first step
    float eA = emb[(size_t)imax(L - 2, 0) * K2_ + n];
    float eB = emb[(size_t)imax(L - 3, 0) * K2_ + n];
    float eC = emb[(size_t)imax(L - 4, 0) * K2_ + n];
    float eD = emb[(size_t)imax(L - 5, 0) * K2_ + n];
    vv = ub * X2F(e0);                                    // w_0 = E_{L-1}.*u_0
    int s = 0;
    for (; s + 4 <= cnt; s += 4) {
      int j4 = imax(L - 6 - s, 0), j5 = imax(L - 7 - s, 0);
      int j6 = imax(L - 8 - s, 0), j7 = imax(L - 9 - s, 0);
      BSTEP_R(eA, j4);
      BSTEP_N(eB, j5);
      BSTEP_N(eC, j6);
      BSTEP_N(eD, j7);
    }
    int rem = cnt - s;
    if (rem > 0) BSTEP_R(eA, 0);
    if (rem > 1) BSTEP_N(eB, 0);
    if (rem > 2) BSTEP_N(eC, 0);

    sU[lane] = ub;              // publish final u
    if (lane == 0) sCb[0] = C;
  }

  // ---- gold score (both waves, stride 128) ----
  float gold = 0.0f;
  const int* labb = lab + b * T_;
  for (int tt = tid; tt < L; tt += 128) {
    int l1 = labb[tt];
    int l0 = (tt == 0) ? 50 : labb[tt - 1];
    gold += emb[(size_t)tt * K2_ + l1] + tr[l1 * K2_ + l0];
  }
  if (tid == 0) gold += tr[(K2_ - 1) * K2_ + labb[L - 1]];  // STOP <- last label
#pragma unroll
  for (int off = 32; off >= 1; off >>= 1)
    gold += __shfl_xor(gold, off, 64);
  if (lane == 0) sG[wave] = gold;

  __syncthreads();

  if (wave == 0) {
    // dot(u, v) + combine log-offsets
    float x = (lane < K2_) ? vv * sU[lane] : 0.0f;
#pragma unroll
    for (int off = 32; off >= 1; off >>= 1)
      x += __shfl_xor(x, off, 64);
    float fwd = (C + sCb[0] + __builtin_amdgcn_logf(x)) * LN2_;
    if (lane == 0) per_b[b] = fwd - (sG[0] + sG[1]);
  }
}

__global__ void reduce_mean_kernel(const float* __restrict__ per_b,
                                   float* __restrict__ out)
{
  const int tid = threadIdx.x;  // 256
  float v = per_b[tid];
#pragma unroll
  for (int off = 32; off >= 1; off >>= 1) v += __shfl_xor(v, off, 64);
  __shared__ float s[4];
  if ((tid & 63) == 0) s[tid >> 6] = v;
  __syncthreads();
  if (tid == 0) out[0] = ((s[0] + s[1]) + (s[2] + s[3])) * (1.0f / (float)B_);
}

extern "C" void kernel_launch(void* const* d_in, const int* in_sizes, int n_in,
                              void* d_out, int out_size, void* d_ws, size_t ws_size,
                              hipStream_t stream) {
  const float* em  = (const float*)d_in[0];   // [B,T,K2] f32
  const float* tr  = (const float*)d_in[1];   // [K2,K2]  f32
  const int*   len = (const int*)d_in[2];     // [B] i32
  const int*   lab = (const int*)d_in[3];     // [B,T] i32
  float* out = (float*)d_out;
  float* ws  = (float*)d_ws;                  // 256 floats of per-batch scores

  crf_fwd_kernel<<<B_, 128, 0, stream>>>(em, tr, len, lab, ws);
  reduce_mean_kernel<<<1, 256, 0, stream>>>(ws, out);
}

// Round 11
// 390.627 us; speedup vs baseline: 1.2998x; 1.0003x over previous
//
#include <hip/hip_runtime.h>

// CRF NLL forward loss. B=256, T=2048, K2=52 (50 labels + START=50 + STOP=51).
// Linear-domain bidirectional recurrence, one chain per wave (R9 structure):
//   wave 0 (fwd): v <- E_t * (M v),   t = 0..h-1      (h = L/2)
//   wave 1 (bwd): u <- M^T (E_t * u), t = L-1..h
//   score = ln2*(Cf + Cb + log2(dot(u,v)))
//
// R17: engine scorecard (cyc/chain-step): LDS = 638 (R9/R16, hand-waitcnt
// proved it's pure data latency) < readlane = 700 (R0) < bpermute = 795 <
// DPP = 940. But R0's readlane-700 was measured with readlane->FMA ADJACENT
// (VALU-writes-SGPR -> VALU-reads hazard ~9cyc paid 52x/step) — a scheduling
// artifact, not an engine property. v_readlane is pure VALU: 2-cyc issue, no
// memory latency, no waitcnt. This kernel bulk-issues 13 readlanes per asm
// block into SGPRs and consumes each block >=13 instructions later
// (RL A, RL B, |fence| FMA A, RL C, |fence| FMA B, RL D, |fence| FMA C, FMA D):
// hazards amortize to zero, step collapses to issue (~250-320cyc predicted).
// Renorm magnitude = first readlane of group A (comp 50 fwd / comp 0 bwd);
// rcp/log run parallel to the FMA stream. NO LDS in the loop.
// waves_per_eu(1,1) + volatile-asm M defs keep M resident (R11 lesson).
// Renorm every 4 steps by an always-positive component (growth < 2^95).

#define B_    256
#define T_    2048
#define K2_   52
#define LOG2E_ 1.4426950408889634f
#define LN2_   0.6931471805599453f

__device__ __forceinline__ int imin(int a, int b) { return a < b ? a : b; }
__device__ __forceinline__ int imax(int a, int b) { return a > b ? a : b; }

#define X2F(e) __builtin_amdgcn_exp2f((e) * LOG2E_)
#define SBAR   __builtin_amdgcn_sched_barrier(0)

#define FORALL52(F) \
  F(0) F(1) F(2) F(3) F(4) F(5) F(6) F(7) F(8) F(9) F(10) F(11) F(12) F(13) \
  F(14) F(15) F(16) F(17) F(18) F(19) F(20) F(21) F(22) F(23) F(24) F(25) \
  F(26) F(27) F(28) F(29) F(30) F(31) F(32) F(33) F(34) F(35) F(36) F(37) \
  F(38) F(39) F(40) F(41) F(42) F(43) F(44) F(45) F(46) F(47) F(48) F(49) \
  F(50) F(51)

// M defs: volatile asm (unsinkable) so the 52 values stay register-resident.
// Forward: lane n holds row n (MF_i = exp(tr[n][i])). Backward: col n.
#define DECLMF(i) float MF_##i; { float _t = tr[n * K2_ + i] * LOG2E_; \
  asm volatile("v_exp_f32 %0, %1\n\ts_nop 1" : "=v"(MF_##i) : "v"(_t)); }
#define DECLMB(i) float MB_##i; { float _t = tr[i * K2_ + n] * LOG2E_; \
  asm volatile("v_exp_f32 %0, %1\n\ts_nop 1" : "=v"(MB_##i) : "v"(_t)); }

// Bulk 13x v_readlane of state components c0..c12 into SGPRs P0..P12.
// All 13 are independent (read lane ck of SRC); 2-cyc VALU issue each.
#define RL13(P, SRC, c0,c1,c2,c3,c4,c5,c6,c7,c8,c9,c10,c11,c12) \
  float P##0,P##1,P##2,P##3,P##4,P##5,P##6,P##7,P##8,P##9,P##10,P##11,P##12; \
  asm volatile( \
    "v_readlane_b32 %0, %13, " #c0 "\n\t" \
    "v_readlane_b32 %1, %13, " #c1 "\n\t" \
    "v_readlane_b32 %2, %13, " #c2 "\n\t" \
    "v_readlane_b32 %3, %13, " #c3 "\n\t" \
    "v_readlane_b32 %4, %13, " #c4 "\n\t" \
    "v_readlane_b32 %5, %13, " #c5 "\n\t" \
    "v_readlane_b32 %6, %13, " #c6 "\n\t" \
    "v_readlane_b32 %7, %13, " #c7 "\n\t" \
    "v_readlane_b32 %8, %13, " #c8 "\n\t" \
    "v_readlane_b32 %9, %13, " #c9 "\n\t" \
    "v_readlane_b32 %10, %13, " #c10 "\n\t" \
    "v_readlane_b32 %11, %13, " #c11 "\n\t" \
    "v_readlane_b32 %12, %13, " #c12 "\n\t" \
    : "=s"(P##0),"=s"(P##1),"=s"(P##2),"=s"(P##3),"=s"(P##4),"=s"(P##5), \
      "=s"(P##6),"=s"(P##7),"=s"(P##8),"=s"(P##9),"=s"(P##10),"=s"(P##11), \
      "=s"(P##12) \
    : "v"(SRC));

// 13 FMAs: acc[k%8] += M_{ck} * P_k.  One SGPR operand per v_fma (legal).
#define FMA13(MP, P, c0,c1,c2,c3,c4,c5,c6,c7,c8,c9,c10,c11,c12) \
  _a0 = fmaf(MP##_##c0,  P##0,  _a0); \
  _a1 = fmaf(MP##_##c1,  P##1,  _a1); \
  _a2 = fmaf(MP##_##c2,  P##2,  _a2); \
  _a3 = fmaf(MP##_##c3,  P##3,  _a3); \
  _a4 = fmaf(MP##_##c4,  P##4,  _a4); \
  _a5 = fmaf(MP##_##c5,  P##5,  _a5); \
  _a6 = fmaf(MP##_##c6,  P##6,  _a6); \
  _a7 = fmaf(MP##_##c7,  P##7,  _a7); \
  _a0 = fmaf(MP##_##c8,  P##8,  _a0); \
  _a1 = fmaf(MP##_##c9,  P##9,  _a1); \
  _a2 = fmaf(MP##_##c10, P##10, _a2); \
  _a3 = fmaf(MP##_##c11, P##11, _a3); \
  _a4 = fmaf(MP##_##c12, P##12, _a4);

// Component groups. FWD: renorm comp 50 is A_0. BWD: renorm comp 0 is A_0.
#define GF_A 50,0,1,2,3,4,5,6,7,8,9,10,11
#define GF_B 12,13,14,15,16,17,18,19,20,21,22,23,24
#define GF_C 25,26,27,28,29,30,31,32,33,34,35,36,37
#define GF_D 38,39,40,41,42,43,44,45,46,47,48,49,51
#define GB_A 0,1,2,3,4,5,6,7,8,9,10,11,12
#define GB_B 13,14,15,16,17,18,19,20,21,22,23,24,25
#define GB_C 26,27,28,29,30,31,32,33,34,35,36,37,38
#define GB_D 39,40,41,42,43,44,45,46,47,48,49,50,51

// Interleaved matvec: RL A, RL B, |f| FMA A + RL C, |f| FMA B + RL D, |f|
// FMA C, FMA D.  Every FMA group consumes SGPRs written >=13 instrs earlier.
#define MVCORE(MP, GA, GB, GC, GD) \
    RL13(A_, vv, GA) \
    RL13(B_, vv, GB) \
    SBAR; \
    float _a0=0.f,_a1=0.f,_a2=0.f,_a3=0.f,_a4=0.f,_a5=0.f,_a6=0.f,_a7=0.f; \
    FMA13(MP, A_, GA) \
    RL13(C_, vv, GC) \
    SBAR; \
    FMA13(MP, B_, GB) \
    RL13(D_, vv, GD) \
    SBAR; \
    FMA13(MP, C_, GC) \
    FMA13(MP, D_, GD) \
    float _y = ((_a0+_a1)+(_a2+_a3)) + ((_a4+_a5)+(_a6+_a7));

// ---- forward steps: v' = E_t * (M v); renorm comp 50 = A_0 ----------------
#define FSTEP_R(EV, NEWIDX) do {                                \
    float _ne = emb[(size_t)(NEWIDX) * K2_ + n];                \
    float _E  = X2F(EV);                                        \
    MVCORE(MF, GF_A, GF_B, GF_C, GF_D)                          \
    float _m   = A_0;                                           \
    float _inv = __builtin_amdgcn_rcpf(_m);                     \
    C += __builtin_amdgcn_logf(_m);                             \
    vv = _y * (_inv * _E);                                      \
    EV = _ne;                                                   \
  } while (0)
#define FSTEP_N(EV, NEWIDX) do {                                \
    float _ne = emb[(size_t)(NEWIDX) * K2_ + n];                \
    float _E  = X2F(EV);                                        \
    MVCORE(MF, GF_A, GF_B, GF_C, GF_D)                          \
    vv = _y * _E;                                               \
    EV = _ne;                                                   \
  } while (0)

// ---- backward steps: vv holds w = E.*u; u' = M^T w; w' = u' * E_next ------
#define BSTEP_R(EV, NEWIDX) do {                                \
    float _ne = emb[(size_t)(NEWIDX) * K2_ + n];                \
    float _E  = X2F(EV);                                        \
    MVCORE(MB, GB_A, GB_B, GB_C, GB_D)                          \
    float _m   = A_0;                                           \
    float _inv = __builtin_amdgcn_rcpf(_m);                     \
    C += __builtin_amdgcn_logf(_m);                             \
    ub = _y * _inv;                                             \
    vv = ub * _E;                                               \
    EV = _ne;                                                   \
  } while (0)
#define BSTEP_N(EV, NEWIDX) do {                                \
    float _ne = emb[(size_t)(NEWIDX) * K2_ + n];                \
    float _E  = X2F(EV);                                        \
    MVCORE(MB, GB_A, GB_B, GB_C, GB_D)                          \
    ub = _y;                                                    \
    vv = ub * _E;                                               \
    EV = _ne;                                                   \
  } while (0)

__global__ __launch_bounds__(128)
__attribute__((amdgpu_waves_per_eu(1, 1)))
void crf_fwd_kernel(const float* __restrict__ em,
                    const float* __restrict__ tr,
                    const int*  __restrict__ len,
                    const int*  __restrict__ lab,
                    float* __restrict__ per_b)
{
  const int b    = blockIdx.x;
  const int tid  = threadIdx.x;                      // 128 = 2 waves
  const int wave = tid >> 6;
  const int lane = tid & 63;
  const int n    = (lane < K2_) ? lane : (K2_ - 1);  // lanes 52..63 mirror 51
  const int L    = len[b];
  const int h    = L >> 1;                           // fwd steps; bwd L-h
  const float* emb = em + (size_t)b * (T_ * K2_);

  __shared__ float sU[64];     // backward wave's final u (handoff only)
  __shared__ float sCb[1];     // backward wave's log-offset
  __shared__ float sG[2];      // per-wave gold partials

  float vv, C = 0.0f;

  if (wave == 0) {
    // ---------------- forward half: h steps, rows 0..h-1 ----------------
    FORALL52(DECLMF)
    vv = (lane == 50) ? 1.0f : 0.0f;
    float e0 = emb[0 * K2_ + n];
    float e1 = emb[1 * K2_ + n];
    float e2 = emb[2 * K2_ + n];
    float e3 = emb[3 * K2_ + n];
    int t = 0;
    for (; t + 4 <= h; t += 4) {
      int i4 = imin(t + 4, T_ - 1), i5 = imin(t + 5, T_ - 1);
      int i6 = imin(t + 6, T_ - 1), i7 = imin(t + 7, T_ - 1);
      FSTEP_R(e0, i4);
      FSTEP_N(e1, i5);
      FSTEP_N(e2, i6);
      FSTEP_N(e3, i7);
    }
    int rem = h - t;
    if (rem > 0) FSTEP_R(e0, T_ - 1);
    if (rem > 1) FSTEP_N(e1, T_ - 1);
    if (rem > 2) FSTEP_N(e2, T_ - 1);
  } else {
    // ---------------- backward half: L-h steps, rows L-1 down to h ------
    FORALL52(DECLMB)
    float ub = X2F(tr[(K2_ - 1) * K2_ + n]);              // u_0 = s (STOP row)
    int cnt = L - h;
    float e0 = emb[(size_t)(L - 1) * K2_ + n];            // E for first step
    float eA = emb[(size_t)imax(L - 2, 0) * K2_ + n];
    float eB = emb[(size_t)imax(L - 3, 0) * K2_ + n];
    float eC = emb[(size_t)imax(L - 4, 0) * K2_ + n];
    float eD = emb[(size_t)imax(L - 5, 0) * K2_ + n];
    vv = ub * X2F(e0);                                    // w_0 = E_{L-1}.*u_0
    int s = 0;
    for (; s + 4 <= cnt; s += 4) {
      int j4 = imax(L - 6 - s, 0), j5 = imax(L - 7 - s, 0);
      int j6 = imax(L - 8 - s, 0), j7 = imax(L - 9 - s, 0);
      BSTEP_R(eA, j4);
      BSTEP_N(eB, j5);
      BSTEP_N(eC, j6);
      BSTEP_N(eD, j7);
    }
    int rem = cnt - s;
    if (rem > 0) BSTEP_R(eA, 0);
    if (rem > 1) BSTEP_N(eB, 0);
    if (rem > 2) BSTEP_N(eC, 0);

    sU[lane] = ub;              // publish final u
    if (lane == 0) sCb[0] = C;
  }

  // ---- gold score (both waves, stride 128) ----
  float gold = 0.0f;
  const int* labb = lab + b * T_;
  for (int tt = tid; tt < L; tt += 128) {
    int l1 = labb[tt];
    int l0 = (tt == 0) ? 50 : labb[tt - 1];
    gold += emb[(size_t)tt * K2_ + l1] + tr[l1 * K2_ + l0];
  }
  if (tid == 0) gold += tr[(K2_ - 1) * K2_ + labb[L - 1]];  // STOP <- last label
#pragma unroll
  for (int off = 32; off >= 1; off >>= 1)
    gold += __shfl_xor(gold, off, 64);
  if (lane == 0) sG[wave] = gold;

  __syncthreads();

  if (wave == 0) {
    // dot(u, v) + combine log-offsets
    float x = (lane < K2_) ? vv * sU[lane] : 0.0f;
#pragma unroll
    for (int off = 32; off >= 1; off >>= 1)
      x += __shfl_xor(x, off, 64);
    float fwd = (C + sCb[0] + __builtin_amdgcn_logf(x)) * LN2_;
    if (lane == 0) per_b[b] = fwd - (sG[0] + sG[1]);
  }
}

__global__ void reduce_mean_kernel(const float* __restrict__ per_b,
                                   float* __restrict__ out)
{
  const int tid = threadIdx.x;  // 256
  float v = per_b[tid];
#pragma unroll
  for (int off = 32; off >= 1; off >>= 1) v += __shfl_xor(v, off, 64);
  __shared__ float s[4];
  if ((tid & 63) == 0) s[tid >> 6] = v;
  __syncthreads();
  if (tid == 0) out[0] = ((s[0] + s[1]) + (s[2] + s[3])) * (1.0f / (float)B_);
}

extern "C" void kernel_launch(void* const* d_in, const int* in_sizes, int n_in,
                              void* d_out, int out_size, void* d_ws, size_t ws_size,
                              hipStream_t stream) {
  const float* em  = (const float*)d_in[0];   // [B,T,K2] f32
  const float* tr  = (const float*)d_in[1];   // [K2,K2]  f32
  const int*   len = (const int*)d_in[2];     // [B] i32
  const int*   lab = (const int*)d_in[3];     // [B,T] i32
  float* out = (float*)d_out;
  float* ws  = (float*)d_ws;                  // 256 floats of per-batch scores

  crf_fwd_kernel<<<B_, 128, 0, stream>>>(em, tr, len, lab, ws);
  reduce_mean_kernel<<<1, 256, 0, stream>>>(ws, out);
}